// Round 1
// baseline (4330.773 us; speedup 1.0000x reference)
//
#include <hip/hip_runtime.h>
#include <hip/hip_bf16.h>
#include <cstddef>

#define NB 2
#define SEQ 2048
#define DIMX 4096
#define NH 16
#define NKV 4
#define HD 64
#define LATENT 1024
#define KVD 256
#define QKVN 1536
#define BS (NB*SEQ)

// ---------------- generic fp32 GEMM: C[M][N] = A[M][K] @ W[N][K]^T (+bias) ----------------
// CONV=1: A is a virtual [M][Cch*3] matrix, A[t][c*3+j] = src[t+j-2][c] (causal, zero-pad per 2048-batch)
template<int CONV>
__global__ __launch_bounds__(256)
void gemm_f32(const float* __restrict__ A, const float* __restrict__ W,
              const float* __restrict__ bias, float* __restrict__ C,
              int M, int N, int K, int Cch)
{
    __shared__ float As[16][64];
    __shared__ float Bs[16][64];
    const int n0 = blockIdx.x * 64, m0 = blockIdx.y * 64;
    const int tx = threadIdx.x, ty = threadIdx.y;
    const int tid = ty * 16 + tx;
    const int lm = tid >> 2;          // 0..63
    const int lk = (tid & 3) << 2;    // 0,4,8,12
    float acc[4][4] = {};
    for (int k0 = 0; k0 < K; k0 += 16) {
        if (!CONV) {
            const float4 a4 = *reinterpret_cast<const float4*>(&A[(size_t)(m0 + lm) * K + k0 + lk]);
            As[lk+0][lm] = a4.x; As[lk+1][lm] = a4.y; As[lk+2][lm] = a4.z; As[lk+3][lm] = a4.w;
        } else {
            const int t = m0 + lm;
            const int s = t & (SEQ - 1);
            #pragma unroll
            for (int i = 0; i < 4; i++) {
                const int k = k0 + lk + i;
                const int c = k / 3;
                const int j = k - c * 3;
                float v = 0.f;
                if (s + j >= 2) v = A[(size_t)(t + j - 2) * Cch + c];
                As[lk+i][lm] = v;
            }
        }
        const float4 b4 = *reinterpret_cast<const float4*>(&W[(size_t)(n0 + lm) * K + k0 + lk]);
        Bs[lk+0][lm] = b4.x; Bs[lk+1][lm] = b4.y; Bs[lk+2][lm] = b4.z; Bs[lk+3][lm] = b4.w;
        __syncthreads();
        #pragma unroll
        for (int kk = 0; kk < 16; kk++) {
            const float4 a = *reinterpret_cast<const float4*>(&As[kk][ty << 2]);
            const float4 b = *reinterpret_cast<const float4*>(&Bs[kk][tx << 2]);
            const float av[4] = {a.x, a.y, a.z, a.w};
            const float bv[4] = {b.x, b.y, b.z, b.w};
            #pragma unroll
            for (int i = 0; i < 4; i++)
                #pragma unroll
                for (int j = 0; j < 4; j++)
                    acc[i][j] += av[i] * bv[j];
        }
        __syncthreads();
    }
    float bj[4] = {0.f, 0.f, 0.f, 0.f};
    if (bias != nullptr) {
        #pragma unroll
        for (int j = 0; j < 4; j++) bj[j] = bias[n0 + (tx << 2) + j];
    }
    #pragma unroll
    for (int i = 0; i < 4; i++) {
        float4 o = make_float4(acc[i][0] + bj[0], acc[i][1] + bj[1],
                               acc[i][2] + bj[2], acc[i][3] + bj[3]);
        *reinterpret_cast<float4*>(&C[(size_t)(m0 + (ty << 2) + i) * N + n0 + (tx << 2)]) = o;
    }
}

// ---------------- grouped causal conv1 (k=3, 64 in-ch and 64 out-ch per group) ----------------
// grid: (SEQ/64, NB, groups), block 256. Reads qkv[.., coloff + g*64 + ic], writes out[t][g*64+oc]
__global__ __launch_bounds__(256)
void conv1_grouped(const float* __restrict__ qkv, int coloff,
                   const float* __restrict__ w, const float* __restrict__ bias,
                   float* __restrict__ out, int CH)
{
    const int t0 = blockIdx.x * 64;
    const int b  = blockIdx.y;
    const int g  = blockIdx.z;
    __shared__ float xs[66][64];   // tokens t0-2 .. t0+63
    for (int idx = threadIdx.x; idx < 66 * 64; idx += 256) {
        const int i = idx >> 6, ic = idx & 63;
        const int tt = t0 + i - 2;
        xs[i][ic] = (tt >= 0) ? qkv[(size_t)(b * SEQ + tt) * QKVN + coloff + g * 64 + ic] : 0.f;
    }
    __syncthreads();
    const int oc = threadIdx.x & 63;
    const int ibase = (threadIdx.x >> 6) * 16;   // wave id * 16 tokens
    float acc[16];
    const float bv = bias[g * 64 + oc];
    #pragma unroll
    for (int i = 0; i < 16; i++) acc[i] = bv;
    const float* wp = w + (size_t)(g * 64 + oc) * 192;   // [ic*3 + j]
    for (int ic = 0; ic < 64; ic++) {
        const float w0 = wp[ic * 3 + 0], w1 = wp[ic * 3 + 1], w2 = wp[ic * 3 + 2];
        float xv[18];
        #pragma unroll
        for (int r = 0; r < 18; r++) xv[r] = xs[ibase + r][ic];
        #pragma unroll
        for (int i = 0; i < 16; i++) acc[i] += w0 * xv[i] + w1 * xv[i + 1] + w2 * xv[i + 2];
    }
    #pragma unroll
    for (int i = 0; i < 16; i++)
        out[(size_t)(b * SEQ + t0 + ibase + i) * CH + g * 64 + oc] = acc[i];
}

// ---------------- head means + shifted-v build (transposed to (B,NKV,S,HD)) ----------------
__global__ __launch_bounds__(64)
void meanv_kernel(const float* __restrict__ qkv, float* __restrict__ qmean,
                  float* __restrict__ kmean, float* __restrict__ vT)
{
    const int t = blockIdx.x, d = threadIdx.x;
    const int b = t >> 11, s = t & (SEQ - 1);
    const float* row = qkv + (size_t)t * QKVN;
    float qs = 0.f;
    #pragma unroll
    for (int h = 0; h < NH; h++) qs += row[h * 64 + d];
    qmean[t * 64 + d] = qs * (1.f / NH);
    float ks = 0.f;
    #pragma unroll
    for (int h = 0; h < NKV; h++) ks += row[LATENT + h * 64 + d];
    kmean[t * 64 + d] = ks * (1.f / NKV);
    #pragma unroll
    for (int g = 0; g < NKV; g++) {
        const int c = g * 64 + d;
        float v;
        if (c < 128) v = row[LATENT + KVD + c];
        else         v = (s > 0) ? qkv[(size_t)(t - 1) * QKVN + LATENT + KVD + 128 + (c - 128)] : 0.f;
        vT[((size_t)(b * NKV + g) * SEQ + s) * 64 + d] = v;
    }
}

// ---------------- +0.5*mean, l2norm, rope, transpose to (B,H,S,D) ----------------
// grid: (BS, NH+NKV), block 64 (one wave per (token, head))
__global__ __launch_bounds__(64)
void qk_final(const float* __restrict__ qc2, const float* __restrict__ kc2,
              const float* __restrict__ qmean, const float* __restrict__ kmean,
              const float* __restrict__ key_temp,
              float* __restrict__ qT, float* __restrict__ kT)
{
    const int t = blockIdx.x, hh = blockIdx.y, d = threadIdx.x;
    const int b = t >> 11, s = t & (SEQ - 1);
    float val;
    if (hh < NH) val = qc2[(size_t)t * LATENT + hh * 64 + d]        + 0.5f * kmean[t * 64 + d];
    else         val = kc2[(size_t)t * KVD    + (hh - NH) * 64 + d] + 0.5f * qmean[t * 64 + d];
    float ss = val * val;
    #pragma unroll
    for (int off = 32; off >= 1; off >>= 1) ss += __shfl_xor(ss, off);
    const float n = sqrtf(ss);
    val = val / fmaxf(n, 1e-12f);
    if (hh >= NH) val *= key_temp[0];
    // rope: pairs (2i, 2i+1)
    const int i = d >> 1;
    const float inv = powf(10000.f, -(float)(2 * i) * (1.f / HD));
    const float ang = (float)s * inv;
    const float cv = cosf(ang), sv = sinf(ang);
    const float partner = __shfl_xor(val, 1);
    const float x1 = (d & 1) ? partner : val;
    const float x2 = (d & 1) ? val : partner;
    const float o = (d & 1) ? (x1 * sv + x2 * cv) : (x1 * cv - x2 * sv);
    if (hh < NH) qT[((size_t)(b * NH + hh) * SEQ + s) * 64 + d] = o;
    else         kT[((size_t)(b * NKV + (hh - NH)) * SEQ + s) * 64 + d] = o;
}

// ---------------- causal GQA attention ----------------
// scores = q.k/8 with |q|=1, |k|=8  =>  scores in [-1,1]: no online max needed.
// grid: (SEQ/64, NB*NH), block 64: each lane owns one q row (q,acc in regs), K/V tiles in LDS.
__global__ __launch_bounds__(64)
void attn_kernel(const float* __restrict__ qT, const float* __restrict__ kT,
                 const float* __restrict__ vT, float* __restrict__ attn_out)
{
    const int qt = blockIdx.x;
    const int bh = blockIdx.y;
    const int b = bh >> 4, h = bh & 15;
    const int g = h >> 2;
    const int lane = threadIdx.x;
    const int qrow = qt * 64 + lane;
    const float* qp = qT + ((size_t)(b * NH + h) * SEQ + qrow) * 64;
    float q[64];
    #pragma unroll
    for (int d4 = 0; d4 < 16; d4++) {
        const float4 t4 = *reinterpret_cast<const float4*>(qp + d4 * 4);
        q[d4*4+0] = t4.x; q[d4*4+1] = t4.y; q[d4*4+2] = t4.z; q[d4*4+3] = t4.w;
    }
    float acc[64] = {};
    float lsum = 0.f;
    __shared__ float Ks[32][64];
    __shared__ float Vs[32][64];
    const float* kbase = kT + (size_t)(b * NKV + g) * SEQ * 64;
    const float* vbase = vT + (size_t)(b * NKV + g) * SEQ * 64;
    const int kcount = (qt + 1) * 64;   // multiple of 32
    for (int k0 = 0; k0 < kcount; k0 += 32) {
        __syncthreads();
        for (int idx = lane; idx < 32 * 16; idx += 64) {
            const int kk = idx >> 4, d4 = idx & 15;
            *reinterpret_cast<float4*>(&Ks[kk][d4*4]) =
                *reinterpret_cast<const float4*>(&kbase[(size_t)(k0 + kk) * 64 + d4 * 4]);
            *reinterpret_cast<float4*>(&Vs[kk][d4*4]) =
                *reinterpret_cast<const float4*>(&vbase[(size_t)(k0 + kk) * 64 + d4 * 4]);
        }
        __syncthreads();
        #pragma unroll 1
        for (int kk = 0; kk < 32; kk++) {
            float sdot = 0.f;
            #pragma unroll
            for (int d4 = 0; d4 < 16; d4++) {
                const float4 kv = *reinterpret_cast<const float4*>(&Ks[kk][d4 * 4]);
                sdot += q[d4*4+0]*kv.x + q[d4*4+1]*kv.y + q[d4*4+2]*kv.z + q[d4*4+3]*kv.w;
            }
            const float p = (k0 + kk <= qrow) ? expf(sdot * 0.125f) : 0.f;
            lsum += p;
            #pragma unroll
            for (int d4 = 0; d4 < 16; d4++) {
                const float4 vv = *reinterpret_cast<const float4*>(&Vs[kk][d4 * 4]);
                acc[d4*4+0] += p * vv.x; acc[d4*4+1] += p * vv.y;
                acc[d4*4+2] += p * vv.z; acc[d4*4+3] += p * vv.w;
            }
        }
    }
    const float invl = 1.f / lsum;
    float* op = attn_out + (size_t)(b * SEQ + qrow) * LATENT + h * 64;
    #pragma unroll
    for (int d4 = 0; d4 < 16; d4++) {
        const float4 o = make_float4(acc[d4*4+0]*invl, acc[d4*4+1]*invl,
                                     acc[d4*4+2]*invl, acc[d4*4+3]*invl);
        *reinterpret_cast<float4*>(op + d4 * 4) = o;
    }
}

extern "C" void kernel_launch(void* const* d_in, const int* in_sizes, int n_in,
                              void* d_out, int out_size, void* d_ws, size_t ws_size,
                              hipStream_t stream)
{
    const float* x       = (const float*)d_in[0];
    const float* w_qkv   = (const float*)d_in[1];
    const float* w_o     = (const float*)d_in[2];
    const float* qc1_w   = (const float*)d_in[3];
    const float* qc1_b   = (const float*)d_in[4];
    const float* qc2_w   = (const float*)d_in[5];
    const float* qc2_b   = (const float*)d_in[6];
    const float* kc1_w   = (const float*)d_in[7];
    const float* kc1_b   = (const float*)d_in[8];
    const float* kc2_w   = (const float*)d_in[9];
    const float* kc2_b   = (const float*)d_in[10];
    const float* key_temp = (const float*)d_in[11];

    float* ws = (float*)d_ws;
    float* qkv   = ws;  ws += (size_t)BS * QKVN;    // 6,291,456
    float* qc1   = ws;  ws += (size_t)BS * LATENT;  // 4,194,304
    float* qc2   = ws;  ws += (size_t)BS * LATENT;
    float* kc1   = ws;  ws += (size_t)BS * KVD;     // 1,048,576
    float* kc2   = ws;  ws += (size_t)BS * KVD;
    float* qmean = ws;  ws += (size_t)BS * HD;      // 262,144
    float* kmean = ws;  ws += (size_t)BS * HD;
    float* qT    = ws;  ws += (size_t)BS * LATENT;
    float* kT    = ws;  ws += (size_t)BS * KVD;
    float* vT    = ws;  ws += (size_t)BS * KVD;
    float* attn  = ws;  ws += (size_t)BS * LATENT;
    // total ~27.8M floats = ~111 MB of d_ws

    float* outp = (float*)d_out;
    const dim3 blk(16, 16);

    // 1. qkv projection
    gemm_f32<0><<<dim3(QKVN / 64, BS / 64), blk, 0, stream>>>(x, w_qkv, nullptr, qkv, BS, QKVN, DIMX, 0);
    // 2. means + shifted v
    meanv_kernel<<<dim3(BS), 64, 0, stream>>>(qkv, qmean, kmean, vT);
    // 3. grouped conv1
    conv1_grouped<<<dim3(SEQ / 64, NB, NH),  256, 0, stream>>>(qkv, 0,      qc1_w, qc1_b, qc1, LATENT);
    conv1_grouped<<<dim3(SEQ / 64, NB, NKV), 256, 0, stream>>>(qkv, LATENT, kc1_w, kc1_b, kc1, KVD);
    // 4. full conv2 as shifted GEMM
    gemm_f32<1><<<dim3(LATENT / 64, BS / 64), blk, 0, stream>>>(qc1, qc2_w, qc2_b, qc2, BS, LATENT, LATENT * 3, LATENT);
    gemm_f32<1><<<dim3(KVD / 64,    BS / 64), blk, 0, stream>>>(kc1, kc2_w, kc2_b, kc2, BS, KVD,    KVD * 3,    KVD);
    // 5. +0.5*mean, l2norm, rope, transpose
    qk_final<<<dim3(BS, NH + NKV), 64, 0, stream>>>(qc2, kc2, qmean, kmean, key_temp, qT, kT);
    // 6. causal GQA attention
    attn_kernel<<<dim3(SEQ / 64, NB * NH), 64, 0, stream>>>(qT, kT, vT, attn);
    // 7. output projection
    gemm_f32<0><<<dim3(DIMX / 64, BS / 64), blk, 0, stream>>>(attn, w_o, nullptr, outp, BS, DIMX, LATENT, 0);
}

// Round 3
// 1945.208 us; speedup vs baseline: 2.2264x; 2.2264x over previous
//
#include <hip/hip_runtime.h>
#include <hip/hip_bf16.h>
#include <cstddef>

#define NB 2
#define SEQ 2048
#define DIMX 4096
#define NH 16
#define NKV 4
#define HD 64
#define LATENT 1024
#define KVD 256
#define QKVN 1536
#define BS (NB*SEQ)

typedef __attribute__((ext_vector_type(8))) short short8v;   // 8 bf16 = 4 VGPR
typedef __attribute__((ext_vector_type(4))) float f32x4;

static __device__ __forceinline__ unsigned short f2bf(float f) {
    union { float f; unsigned u; } v; v.f = f;
    unsigned r = v.u + 0x7fffu + ((v.u >> 16) & 1u);
    return (unsigned short)(r >> 16);
}

// ---------------- generic fp32 GEMM: C[M][N] = A[M][K] @ W[N][K]^T (+bias) ----------------
template<int CONV>
__global__ __launch_bounds__(256)
void gemm_f32(const float* __restrict__ A, const float* __restrict__ W,
              const float* __restrict__ bias, float* __restrict__ C,
              int M, int N, int K, int Cch)
{
    __shared__ float As[16][64];
    __shared__ float Bs[16][64];
    const int n0 = blockIdx.x * 64, m0 = blockIdx.y * 64;
    const int tx = threadIdx.x, ty = threadIdx.y;
    const int tid = ty * 16 + tx;
    const int lm = tid >> 2;
    const int lk = (tid & 3) << 2;
    float acc[4][4] = {};
    for (int k0 = 0; k0 < K; k0 += 16) {
        if (!CONV) {
            const float4 a4 = *reinterpret_cast<const float4*>(&A[(size_t)(m0 + lm) * K + k0 + lk]);
            As[lk+0][lm] = a4.x; As[lk+1][lm] = a4.y; As[lk+2][lm] = a4.z; As[lk+3][lm] = a4.w;
        } else {
            const int t = m0 + lm;
            const int s = t & (SEQ - 1);
            #pragma unroll
            for (int i = 0; i < 4; i++) {
                const int k = k0 + lk + i;
                const int c = k / 3;
                const int j = k - c * 3;
                float v = 0.f;
                if (s + j >= 2) v = A[(size_t)(t + j - 2) * Cch + c];
                As[lk+i][lm] = v;
            }
        }
        const float4 b4 = *reinterpret_cast<const float4*>(&W[(size_t)(n0 + lm) * K + k0 + lk]);
        Bs[lk+0][lm] = b4.x; Bs[lk+1][lm] = b4.y; Bs[lk+2][lm] = b4.z; Bs[lk+3][lm] = b4.w;
        __syncthreads();
        #pragma unroll
        for (int kk = 0; kk < 16; kk++) {
            const float4 a = *reinterpret_cast<const float4*>(&As[kk][ty << 2]);
            const float4 b = *reinterpret_cast<const float4*>(&Bs[kk][tx << 2]);
            const float av[4] = {a.x, a.y, a.z, a.w};
            const float bv[4] = {b.x, b.y, b.z, b.w};
            #pragma unroll
            for (int i = 0; i < 4; i++)
                #pragma unroll
                for (int j = 0; j < 4; j++)
                    acc[i][j] += av[i] * bv[j];
        }
        __syncthreads();
    }
    float bj[4] = {0.f, 0.f, 0.f, 0.f};
    if (bias != nullptr) {
        #pragma unroll
        for (int j = 0; j < 4; j++) bj[j] = bias[n0 + (tx << 2) + j];
    }
    #pragma unroll
    for (int i = 0; i < 4; i++) {
        float4 o = make_float4(acc[i][0] + bj[0], acc[i][1] + bj[1],
                               acc[i][2] + bj[2], acc[i][3] + bj[3]);
        *reinterpret_cast<float4*>(&C[(size_t)(m0 + (ty << 2) + i) * N + n0 + (tx << 2)]) = o;
    }
}

// ---------------- grouped causal conv1 ----------------
__global__ __launch_bounds__(256)
void conv1_grouped(const float* __restrict__ qkv, int coloff,
                   const float* __restrict__ w, const float* __restrict__ bias,
                   float* __restrict__ out, int CH)
{
    const int t0 = blockIdx.x * 64;
    const int b  = blockIdx.y;
    const int g  = blockIdx.z;
    __shared__ float xs[66][64];
    for (int idx = threadIdx.x; idx < 66 * 64; idx += 256) {
        const int i = idx >> 6, ic = idx & 63;
        const int tt = t0 + i - 2;
        xs[i][ic] = (tt >= 0) ? qkv[(size_t)(b * SEQ + tt) * QKVN + coloff + g * 64 + ic] : 0.f;
    }
    __syncthreads();
    const int oc = threadIdx.x & 63;
    const int ibase = (threadIdx.x >> 6) * 16;
    float acc[16];
    const float bv = bias[g * 64 + oc];
    #pragma unroll
    for (int i = 0; i < 16; i++) acc[i] = bv;
    const float* wp = w + (size_t)(g * 64 + oc) * 192;
    for (int ic = 0; ic < 64; ic++) {
        const float w0 = wp[ic * 3 + 0], w1 = wp[ic * 3 + 1], w2 = wp[ic * 3 + 2];
        float xv[18];
        #pragma unroll
        for (int r = 0; r < 18; r++) xv[r] = xs[ibase + r][ic];
        #pragma unroll
        for (int i = 0; i < 16; i++) acc[i] += w0 * xv[i] + w1 * xv[i + 1] + w2 * xv[i + 2];
    }
    #pragma unroll
    for (int i = 0; i < 16; i++)
        out[(size_t)(b * SEQ + t0 + ibase + i) * CH + g * 64 + oc] = acc[i];
}

// ---------------- head means + shifted-v build (row-major bf16) ----------------
__global__ __launch_bounds__(64)
void meanv_kernel(const float* __restrict__ qkv, float* __restrict__ qmean,
                  float* __restrict__ kmean, unsigned short* __restrict__ vRow)
{
    const int t = blockIdx.x, d = threadIdx.x;
    const int b = t >> 11, s = t & (SEQ - 1);
    const float* row = qkv + (size_t)t * QKVN;
    float qs = 0.f;
    #pragma unroll
    for (int h = 0; h < NH; h++) qs += row[h * 64 + d];
    qmean[t * 64 + d] = qs * (1.f / NH);
    float ks = 0.f;
    #pragma unroll
    for (int h = 0; h < NKV; h++) ks += row[LATENT + h * 64 + d];
    kmean[t * 64 + d] = ks * (1.f / NKV);
    #pragma unroll
    for (int g = 0; g < NKV; g++) {
        const int c = g * 64 + d;
        float v;
        if (c < 128) v = row[LATENT + KVD + c];
        else         v = (s > 0) ? qkv[(size_t)(t - 1) * QKVN + LATENT + KVD + 128 + (c - 128)] : 0.f;
        vRow[((size_t)(b * NKV + g) * SEQ + s) * 64 + d] = f2bf(v);
    }
}

// ---------------- V transpose to d-major: vTb[bg][d][S] ----------------
__global__ __launch_bounds__(256)
void vtrans(const unsigned short* __restrict__ vRow, unsigned short* __restrict__ vTb)
{
    const int s0 = blockIdx.x * 64;
    const int bg = blockIdx.y;
    __shared__ unsigned short t[64][72];
    const int tid = threadIdx.x;
    {
        const int r = tid >> 2, c0 = (tid & 3) * 16;
        const unsigned short* p = vRow + ((size_t)bg * SEQ + s0 + r) * 64 + c0;
        const short8v a = *reinterpret_cast<const short8v*>(p);
        const short8v bv = *reinterpret_cast<const short8v*>(p + 8);
        #pragma unroll
        for (int j = 0; j < 8; j++) { t[r][c0 + j] = (unsigned short)a[j]; t[r][c0 + 8 + j] = (unsigned short)bv[j]; }
    }
    __syncthreads();
    {
        const int d = tid >> 2, ss = (tid & 3) * 16;
        short8v o0, o1;
        #pragma unroll
        for (int j = 0; j < 8; j++) { o0[j] = (short)t[ss + j][d]; o1[j] = (short)t[ss + 8 + j][d]; }
        unsigned short* op = vTb + ((size_t)bg * 64 + d) * SEQ + s0 + ss;
        *reinterpret_cast<short8v*>(op) = o0;
        *reinterpret_cast<short8v*>(op + 8) = o1;
    }
}

// ---------------- +0.5*mean, l2norm, rope -> bf16 (B,H,S,D) ----------------
__global__ __launch_bounds__(64)
void qk_final(const float* __restrict__ qc2, const float* __restrict__ kc2,
              const float* __restrict__ qmean, const float* __restrict__ kmean,
              const float* __restrict__ key_temp,
              unsigned short* __restrict__ qTb, unsigned short* __restrict__ kTb)
{
    const int t = blockIdx.x, hh = blockIdx.y, d = threadIdx.x;
    const int b = t >> 11, s = t & (SEQ - 1);
    float val;
    if (hh < NH) val = qc2[(size_t)t * LATENT + hh * 64 + d]        + 0.5f * kmean[t * 64 + d];
    else         val = kc2[(size_t)t * KVD    + (hh - NH) * 64 + d] + 0.5f * qmean[t * 64 + d];
    float ss = val * val;
    #pragma unroll
    for (int off = 32; off >= 1; off >>= 1) ss += __shfl_xor(ss, off);
    const float n = sqrtf(ss);
    val = val / fmaxf(n, 1e-12f);
    if (hh >= NH) val *= key_temp[0];
    const int i = d >> 1;
    const float inv = powf(10000.f, -(float)(2 * i) * (1.f / HD));
    const float ang = (float)s * inv;
    const float cv = cosf(ang), sv = sinf(ang);
    const float partner = __shfl_xor(val, 1);
    const float x1 = (d & 1) ? partner : val;
    const float x2 = (d & 1) ? val : partner;
    const float o = (d & 1) ? (x1 * sv + x2 * cv) : (x1 * cv - x2 * sv);
    if (hh < NH) qTb[((size_t)(b * NH + hh) * SEQ + s) * 64 + d] = f2bf(o);
    else         kTb[((size_t)(b * NKV + (hh - NH)) * SEQ + s) * 64 + d] = f2bf(o);
}

// ---------------- MFMA causal GQA attention ----------------
// one wave per 32 q-rows; scores in [-1,1] => plain exp accumulation, no online max.
// frag layouts (16x16x32 bf16): A row=lane&15,k=8*(lane>>4)+j; B col=lane&15,k=8*(lane>>4)+j;
// C/D col=lane&15,row=4*(lane>>4)+reg  [m89-verified]
__global__ __launch_bounds__(64)
void attn_mfma(const unsigned short* __restrict__ qTb, const unsigned short* __restrict__ kTb,
               const unsigned short* __restrict__ vTb, float* __restrict__ attn_out)
{
    const int qt = 63 - blockIdx.x;          // longest tiles dispatched first
    const int bh = blockIdx.y;
    const int b = bh >> 4, h = bh & 15, g = h >> 2;
    const int lane = threadIdx.x;
    const int lg = lane >> 4, lr = lane & 15;
    const int q0 = qt * 32;
    __shared__ __align__(16) unsigned short Plds[2][16][40];   // [mf][row][key], 80B row stride

    short8v qf[2][2];
    const unsigned short* qbase = qTb + ((size_t)(b * NH + h) * SEQ + q0) * 64;
    #pragma unroll
    for (int mf = 0; mf < 2; mf++)
        #pragma unroll
        for (int dc = 0; dc < 2; dc++)
            qf[mf][dc] = *reinterpret_cast<const short8v*>(qbase + (size_t)(mf * 16 + lr) * 64 + dc * 32 + lg * 8);

    f32x4 acc[2][4];
    float lsum[2][4];
    #pragma unroll
    for (int mf = 0; mf < 2; mf++) {
        #pragma unroll
        for (int dt = 0; dt < 4; dt++) acc[mf][dt] = (f32x4){0.f, 0.f, 0.f, 0.f};
        #pragma unroll
        for (int r = 0; r < 4; r++) lsum[mf][r] = 0.f;
    }

    const unsigned short* kbase = kTb + (size_t)(b * NKV + g) * SEQ * 64;
    const unsigned short* vbase = vTb + (size_t)(b * NKV + g) * 64 * SEQ;
    const float EC = 0.125f * 1.44269504f;   // scale * log2(e), use exp2

    for (int c = 0; c <= qt; ++c) {
        const int k0 = c * 32;
        short8v kf[2][2];
        #pragma unroll
        for (int kt = 0; kt < 2; kt++)
            #pragma unroll
            for (int dc = 0; dc < 2; dc++)
                kf[kt][dc] = *reinterpret_cast<const short8v*>(kbase + (size_t)(k0 + kt * 16 + lr) * 64 + dc * 32 + lg * 8);
        short8v vf[4];
        #pragma unroll
        for (int dt = 0; dt < 4; dt++)
            vf[dt] = *reinterpret_cast<const short8v*>(vbase + (size_t)(dt * 16 + lr) * SEQ + k0 + lg * 8);

        f32x4 S[2][2];
        #pragma unroll
        for (int mf = 0; mf < 2; mf++)
            #pragma unroll
            for (int kt = 0; kt < 2; kt++) {
                f32x4 z = (f32x4){0.f, 0.f, 0.f, 0.f};
                z = __builtin_amdgcn_mfma_f32_16x16x32_bf16(qf[mf][0], kf[kt][0], z, 0, 0, 0);
                S[mf][kt] = __builtin_amdgcn_mfma_f32_16x16x32_bf16(qf[mf][1], kf[kt][1], z, 0, 0, 0);
            }

        const bool diag = (c == qt);
        #pragma unroll
        for (int mf = 0; mf < 2; mf++)
            #pragma unroll
            for (int kt = 0; kt < 2; kt++)
                #pragma unroll
                for (int r = 0; r < 4; r++) {
                    float p = exp2f(S[mf][kt][r] * EC);
                    if (diag) {
                        const int q = q0 + mf * 16 + lg * 4 + r;
                        const int key = k0 + kt * 16 + lr;
                        if (key > q) p = 0.f;
                    }
                    lsum[mf][r] += p;
                    Plds[mf][lg * 4 + r][kt * 16 + lr] = f2bf(p);
                }

        #pragma unroll
        for (int mf = 0; mf < 2; mf++) {
            const short8v pa = *reinterpret_cast<const short8v*>(&Plds[mf][lr][lg * 8]);
            #pragma unroll
            for (int dt = 0; dt < 4; dt++)
                acc[mf][dt] = __builtin_amdgcn_mfma_f32_16x16x32_bf16(pa, vf[dt], acc[mf][dt], 0, 0, 0);
        }
    }

    float invl[2][4];
    #pragma unroll
    for (int mf = 0; mf < 2; mf++)
        #pragma unroll
        for (int r = 0; r < 4; r++) {
            float s = lsum[mf][r];
            s += __shfl_xor(s, 1); s += __shfl_xor(s, 2);
            s += __shfl_xor(s, 4); s += __shfl_xor(s, 8);
            invl[mf][r] = 1.f / s;
        }

    #pragma unroll
    for (int mf = 0; mf < 2; mf++)
        #pragma unroll
        for (int dt = 0; dt < 4; dt++)
            #pragma unroll
            for (int r = 0; r < 4; r++) {
                const int q = q0 + mf * 16 + lg * 4 + r;
                attn_out[(size_t)(b * SEQ + q) * LATENT + h * 64 + dt * 16 + lr] = acc[mf][dt][r] * invl[mf][r];
            }
}

extern "C" void kernel_launch(void* const* d_in, const int* in_sizes, int n_in,
                              void* d_out, int out_size, void* d_ws, size_t ws_size,
                              hipStream_t stream)
{
    const float* x       = (const float*)d_in[0];
    const float* w_qkv   = (const float*)d_in[1];
    const float* w_o     = (const float*)d_in[2];
    const float* qc1_w   = (const float*)d_in[3];
    const float* qc1_b   = (const float*)d_in[4];
    const float* qc2_w   = (const float*)d_in[5];
    const float* qc2_b   = (const float*)d_in[6];
    const float* kc1_w   = (const float*)d_in[7];
    const float* kc1_b   = (const float*)d_in[8];
    const float* kc2_w   = (const float*)d_in[9];
    const float* kc2_b   = (const float*)d_in[10];
    const float* key_temp = (const float*)d_in[11];

    char* wsb = (char*)d_ws;
    float* qkv   = (float*)wsb;  wsb += (size_t)BS * QKVN * 4;
    float* qc1   = (float*)wsb;  wsb += (size_t)BS * LATENT * 4;
    float* qc2   = (float*)wsb;  wsb += (size_t)BS * LATENT * 4;
    float* kc1   = (float*)wsb;  wsb += (size_t)BS * KVD * 4;
    float* kc2   = (float*)wsb;  wsb += (size_t)BS * KVD * 4;
    float* qmean = (float*)wsb;  wsb += (size_t)BS * HD * 4;
    float* kmean = (float*)wsb;  wsb += (size_t)BS * HD * 4;
    float* attn  = (float*)wsb;  wsb += (size_t)BS * LATENT * 4;
    unsigned short* qTb  = (unsigned short*)wsb;  wsb += (size_t)BS * LATENT * 2;
    unsigned short* kTb  = (unsigned short*)wsb;  wsb += (size_t)BS * KVD * 2;
    unsigned short* vRow = (unsigned short*)wsb;  wsb += (size_t)BS * KVD * 2;
    unsigned short* vTb  = (unsigned short*)wsb;  wsb += (size_t)BS * KVD * 2;

    float* outp = (float*)d_out;
    const dim3 blk(16, 16);

    gemm_f32<0><<<dim3(QKVN / 64, BS / 64), blk, 0, stream>>>(x, w_qkv, nullptr, qkv, BS, QKVN, DIMX, 0);
    meanv_kernel<<<dim3(BS), 64, 0, stream>>>(qkv, qmean, kmean, vRow);
    vtrans<<<dim3(SEQ / 64, NB * NKV), 256, 0, stream>>>(vRow, vTb);
    conv1_grouped<<<dim3(SEQ / 64, NB, NH),  256, 0, stream>>>(qkv, 0,      qc1_w, qc1_b, qc1, LATENT);
    conv1_grouped<<<dim3(SEQ / 64, NB, NKV), 256, 0, stream>>>(qkv, LATENT, kc1_w, kc1_b, kc1, KVD);
    gemm_f32<1><<<dim3(LATENT / 64, BS / 64), blk, 0, stream>>>(qc1, qc2_w, qc2_b, qc2, BS, LATENT, LATENT * 3, LATENT);
    gemm_f32<1><<<dim3(KVD / 64,    BS / 64), blk, 0, stream>>>(kc1, kc2_w, kc2_b, kc2, BS, KVD,    KVD * 3,    KVD);
    qk_final<<<dim3(BS, NH + NKV), 64, 0, stream>>>(qc2, kc2, qmean, kmean, key_temp, qTb, kTb);
    attn_mfma<<<dim3(SEQ / 32, NB * NH), 64, 0, stream>>>(qTb, kTb, vTb, attn);
    gemm_f32<0><<<dim3(DIMX / 64, BS / 64), blk, 0, stream>>>(attn, w_o, nullptr, outp, BS, DIMX, LATENT, 0);
}

// Round 4
// 495.159 us; speedup vs baseline: 8.7462x; 3.9284x over previous
//
#include <hip/hip_runtime.h>
#include <hip/hip_bf16.h>
#include <cstddef>

#define NB 2
#define SEQ 2048
#define DIMX 4096
#define NH 16
#define NKV 4
#define HD 64
#define LATENT 1024
#define KVD 256
#define QKVN 1536
#define BS (NB*SEQ)
#define SP (SEQ+2)   // padded token rows per batch for conv2 input

typedef __attribute__((ext_vector_type(8))) short short8v;   // 8 bf16 = 4 VGPR
typedef __attribute__((ext_vector_type(4))) float f32x4;
typedef __attribute__((ext_vector_type(4))) unsigned short ushort4v;

static __device__ __forceinline__ unsigned short f2bf(float f) {
    union { float f; unsigned u; } v; v.f = f;
    unsigned r = v.u + 0x7fffu + ((v.u >> 16) & 1u);
    return (unsigned short)(r >> 16);
}

static __device__ __forceinline__ void gload_lds16(const unsigned short* g, unsigned short* l) {
    __builtin_amdgcn_global_load_lds((const __attribute__((address_space(1))) void*)g,
                                     (__attribute__((address_space(3))) void*)l, 16, 0, 0);
}

// ---------------- fp32 -> bf16 cast (vectorized x4) ----------------
__global__ __launch_bounds__(256)
void cast_f2b(const float* __restrict__ in, unsigned short* __restrict__ out, int n4)
{
    const int i = blockIdx.x * 256 + threadIdx.x;
    if (i < n4) {
        const float4 v = *reinterpret_cast<const float4*>(in + (size_t)i * 4);
        ushort4v o = {f2bf(v.x), f2bf(v.y), f2bf(v.z), f2bf(v.w)};
        *reinterpret_cast<ushort4v*>(out + (size_t)i * 4) = o;
    }
}

// ---------------- conv2 weight reorder: wr[o][j*I+c] = w[o][c][j], fp32->bf16 ----------------
__global__ __launch_bounds__(256)
void w3reorder(const float* __restrict__ w, unsigned short* __restrict__ wr, int O, int I)
{
    const int idx = blockIdx.x * 256 + threadIdx.x;
    if (idx < O * I * 3) {
        const int o = idx / (I * 3), rem = idx % (I * 3);
        const int j = rem / I, c = rem % I;
        wr[idx] = f2bf(w[(size_t)o * I * 3 + c * 3 + j]);
    }
}

// ---------------- zero the 2 pad rows per batch of the conv2 input buffers ----------------
__global__ __launch_bounds__(256)
void zero_pad(unsigned short* __restrict__ pq, unsigned short* __restrict__ pk)
{
    const int t = blockIdx.x * 256 + threadIdx.x;
    if (t < 2 * 2 * LATENT) {
        const int b = t / (2 * LATENT), r = (t % (2 * LATENT)) / LATENT, c = t % LATENT;
        pq[((size_t)b * SP + r) * LATENT + c] = 0;
    }
    if (t < 2 * 2 * KVD) {
        const int b = t / (2 * KVD), r = (t % (2 * KVD)) / KVD, c = t % KVD;
        pk[((size_t)b * SP + r) * KVD + c] = 0;
    }
}

// ---------------- bf16 MFMA GEMM: C[M][N] = A[M][K] @ W[N][K]^T (+bias), fp32 out ----------------
// 128x128 tile, BK=32, 4 waves (2x2), 4x4 16x16x32 frags/wave, 2-phase double-buffered
// global_load_lds staging (T3-minimal recipe).
// CONV=1: A is padded conv input [b][SP][Cch] bf16; virtual K = j*Cch + c, row = b*SP + s + j.
template<int CONV>
__global__ __launch_bounds__(256)
void gemm_bf16(const unsigned short* __restrict__ A, const unsigned short* __restrict__ W,
               const float* __restrict__ bias, float* __restrict__ C,
               int M, int N, int K, int Cch)
{
    __shared__ unsigned short Abuf[2][128 * 32];
    __shared__ unsigned short Bbuf[2][128 * 32];
    const int n0 = blockIdx.x * 128, m0 = blockIdx.y * 128;
    const int tid = threadIdx.x;
    const int wave = tid >> 6, lane = tid & 63;
    const int lg = lane >> 4, lr = lane & 15;
    const int wm = (wave & 1) * 64, wn = (wave >> 1) * 64;
    // staging coords: issue i covers tile rows [wave*32 + i*16, +16)
    const int sr = wave * 32 + (lane >> 2);   // issue-0 row
    const int sc = (lane & 3) * 8;            // col (bf16 elems), 16B
    const int bb = m0 / SEQ, s0 = m0 % SEQ;   // CONV: batch/token base (tile within one batch)

    const int NT = K / 32;
    f32x4 acc[4][4];
    #pragma unroll
    for (int i = 0; i < 4; i++)
        #pragma unroll
        for (int j = 0; j < 4; j++) acc[i][j] = (f32x4){0.f, 0.f, 0.f, 0.f};

    auto stage = [&](int buf, int kt) {
        const int k0 = kt * 32;
        const unsigned short* ga0;
        if (!CONV) {
            ga0 = A + (size_t)(m0 + sr) * K + k0 + sc;
        } else {
            const int j = k0 / Cch, c0 = k0 - j * Cch;
            ga0 = A + (size_t)(bb * SP + s0 + j + sr) * Cch + c0 + sc;
        }
        const unsigned short* gb0 = W + (size_t)(n0 + sr) * K + k0 + sc;
        const size_t astep = (size_t)16 * (CONV ? Cch : K);
        #pragma unroll
        for (int i = 0; i < 2; i++) {
            gload_lds16(ga0 + i * astep, &Abuf[buf][(wave * 2 + i) * 512]);
            gload_lds16(gb0 + (size_t)i * 16 * K, &Bbuf[buf][(wave * 2 + i) * 512]);
        }
    };

    stage(0, 0);
    __syncthreads();
    int cur = 0;
    for (int kt = 0; kt < NT; ++kt) {
        if (kt + 1 < NT) stage(cur ^ 1, kt + 1);
        short8v af[4], bf[4];
        #pragma unroll
        for (int mi = 0; mi < 4; mi++)
            af[mi] = *reinterpret_cast<const short8v*>(&Abuf[cur][(wm + mi * 16 + lr) * 32 + lg * 8]);
        #pragma unroll
        for (int ni = 0; ni < 4; ni++)
            bf[ni] = *reinterpret_cast<const short8v*>(&Bbuf[cur][(wn + ni * 16 + lr) * 32 + lg * 8]);
        #pragma unroll
        for (int mi = 0; mi < 4; mi++)
            #pragma unroll
            for (int ni = 0; ni < 4; ni++)
                acc[mi][ni] = __builtin_amdgcn_mfma_f32_16x16x32_bf16(af[mi], bf[ni], acc[mi][ni], 0, 0, 0);
        __syncthreads();
        cur ^= 1;
    }

    // epilogue: C/D layout col=lane&15, row=4*(lane>>4)+reg
    #pragma unroll
    for (int ni = 0; ni < 4; ni++) {
        const int col = n0 + wn + ni * 16 + lr;
        const float bv = bias ? bias[col] : 0.f;
        #pragma unroll
        for (int mi = 0; mi < 4; mi++)
            #pragma unroll
            for (int r = 0; r < 4; r++)
                C[(size_t)(m0 + wm + mi * 16 + lg * 4 + r) * N + col] = acc[mi][ni][r] + bv;
    }
}

// ---------------- grouped causal conv1 -> bf16 padded [b][SP][CH] (rows 0,1 zero) ----------------
__global__ __launch_bounds__(256)
void conv1_grouped(const float* __restrict__ qkv, int coloff,
                   const float* __restrict__ w, const float* __restrict__ bias,
                   unsigned short* __restrict__ out, int CH)
{
    const int t0 = blockIdx.x * 64;
    const int b  = blockIdx.y;
    const int g  = blockIdx.z;
    __shared__ float xs[66][64];
    for (int idx = threadIdx.x; idx < 66 * 64; idx += 256) {
        const int i = idx >> 6, ic = idx & 63;
        const int tt = t0 + i - 2;
        xs[i][ic] = (tt >= 0) ? qkv[(size_t)(b * SEQ + tt) * QKVN + coloff + g * 64 + ic] : 0.f;
    }
    __syncthreads();
    const int oc = threadIdx.x & 63;
    const int ibase = (threadIdx.x >> 6) * 16;
    float acc[16];
    const float bv = bias[g * 64 + oc];
    #pragma unroll
    for (int i = 0; i < 16; i++) acc[i] = bv;
    const float* wp = w + (size_t)(g * 64 + oc) * 192;
    for (int ic = 0; ic < 64; ic++) {
        const float w0 = wp[ic * 3 + 0], w1 = wp[ic * 3 + 1], w2 = wp[ic * 3 + 2];
        float xv[18];
        #pragma unroll
        for (int r = 0; r < 18; r++) xv[r] = xs[ibase + r][ic];
        #pragma unroll
        for (int i = 0; i < 16; i++) acc[i] += w0 * xv[i] + w1 * xv[i + 1] + w2 * xv[i + 2];
    }
    #pragma unroll
    for (int i = 0; i < 16; i++)
        out[((size_t)b * SP + 2 + t0 + ibase + i) * CH + g * 64 + oc] = f2bf(acc[i]);
}

// ---------------- head means + shifted-v build (row-major bf16) ----------------
__global__ __launch_bounds__(64)
void meanv_kernel(const float* __restrict__ qkv, float* __restrict__ qmean,
                  float* __restrict__ kmean, unsigned short* __restrict__ vRow)
{
    const int t = blockIdx.x, d = threadIdx.x;
    const int b = t >> 11, s = t & (SEQ - 1);
    const float* row = qkv + (size_t)t * QKVN;
    float qs = 0.f;
    #pragma unroll
    for (int h = 0; h < NH; h++) qs += row[h * 64 + d];
    qmean[t * 64 + d] = qs * (1.f / NH);
    float ks = 0.f;
    #pragma unroll
    for (int h = 0; h < NKV; h++) ks += row[LATENT + h * 64 + d];
    kmean[t * 64 + d] = ks * (1.f / NKV);
    #pragma unroll
    for (int g = 0; g < NKV; g++) {
        const int c = g * 64 + d;
        float v;
        if (c < 128) v = row[LATENT + KVD + c];
        else         v = (s > 0) ? qkv[(size_t)(t - 1) * QKVN + LATENT + KVD + 128 + (c - 128)] : 0.f;
        vRow[((size_t)(b * NKV + g) * SEQ + s) * 64 + d] = f2bf(v);
    }
}

// ---------------- V transpose to d-major: vTb[bg][d][S] ----------------
__global__ __launch_bounds__(256)
void vtrans(const unsigned short* __restrict__ vRow, unsigned short* __restrict__ vTb)
{
    const int s0 = blockIdx.x * 64;
    const int bg = blockIdx.y;
    __shared__ unsigned short t[64][72];
    const int tid = threadIdx.x;
    {
        const int r = tid >> 2, c0 = (tid & 3) * 16;
        const unsigned short* p = vRow + ((size_t)bg * SEQ + s0 + r) * 64 + c0;
        const short8v a = *reinterpret_cast<const short8v*>(p);
        const short8v bv = *reinterpret_cast<const short8v*>(p + 8);
        #pragma unroll
        for (int j = 0; j < 8; j++) { t[r][c0 + j] = (unsigned short)a[j]; t[r][c0 + 8 + j] = (unsigned short)bv[j]; }
    }
    __syncthreads();
    {
        const int d = tid >> 2, ss = (tid & 3) * 16;
        short8v o0, o1;
        #pragma unroll
        for (int j = 0; j < 8; j++) { o0[j] = (short)t[ss + j][d]; o1[j] = (short)t[ss + 8 + j][d]; }
        unsigned short* op = vTb + ((size_t)bg * 64 + d) * SEQ + s0 + ss;
        *reinterpret_cast<short8v*>(op) = o0;
        *reinterpret_cast<short8v*>(op + 8) = o1;
    }
}

// ---------------- +0.5*mean, l2norm, rope -> bf16 (B,H,S,D) ----------------
__global__ __launch_bounds__(64)
void qk_final(const float* __restrict__ qc2, const float* __restrict__ kc2,
              const float* __restrict__ qmean, const float* __restrict__ kmean,
              const float* __restrict__ key_temp,
              unsigned short* __restrict__ qTb, unsigned short* __restrict__ kTb)
{
    const int t = blockIdx.x, hh = blockIdx.y, d = threadIdx.x;
    const int b = t >> 11, s = t & (SEQ - 1);
    float val;
    if (hh < NH) val = qc2[(size_t)t * LATENT + hh * 64 + d]        + 0.5f * kmean[t * 64 + d];
    else         val = kc2[(size_t)t * KVD    + (hh - NH) * 64 + d] + 0.5f * qmean[t * 64 + d];
    float ss = val * val;
    #pragma unroll
    for (int off = 32; off >= 1; off >>= 1) ss += __shfl_xor(ss, off);
    const float n = sqrtf(ss);
    val = val / fmaxf(n, 1e-12f);
    if (hh >= NH) val *= key_temp[0];
    const int i = d >> 1;
    const float inv = powf(10000.f, -(float)(2 * i) * (1.f / HD));
    const float ang = (float)s * inv;
    const float cv = cosf(ang), sv = sinf(ang);
    const float partner = __shfl_xor(val, 1);
    const float x1 = (d & 1) ? partner : val;
    const float x2 = (d & 1) ? val : partner;
    const float o = (d & 1) ? (x1 * sv + x2 * cv) : (x1 * cv - x2 * sv);
    if (hh < NH) qTb[((size_t)(b * NH + hh) * SEQ + s) * 64 + d] = f2bf(o);
    else         kTb[((size_t)(b * NKV + (hh - NH)) * SEQ + s) * 64 + d] = f2bf(o);
}

// ---------------- MFMA causal GQA attention (bf16 out) ----------------
__global__ __launch_bounds__(64)
void attn_mfma(const unsigned short* __restrict__ qTb, const unsigned short* __restrict__ kTb,
               const unsigned short* __restrict__ vTb, unsigned short* __restrict__ attn_out)
{
    const int qt = 63 - blockIdx.x;
    const int bh = blockIdx.y;
    const int b = bh >> 4, h = bh & 15, g = h >> 2;
    const int lane = threadIdx.x;
    const int lg = lane >> 4, lr = lane & 15;
    const int q0 = qt * 32;
    __shared__ __align__(16) unsigned short Plds[2][16][40];

    short8v qf[2][2];
    const unsigned short* qbase = qTb + ((size_t)(b * NH + h) * SEQ + q0) * 64;
    #pragma unroll
    for (int mf = 0; mf < 2; mf++)
        #pragma unroll
        for (int dc = 0; dc < 2; dc++)
            qf[mf][dc] = *reinterpret_cast<const short8v*>(qbase + (size_t)(mf * 16 + lr) * 64 + dc * 32 + lg * 8);

    f32x4 acc[2][4];
    float lsum[2][4];
    #pragma unroll
    for (int mf = 0; mf < 2; mf++) {
        #pragma unroll
        for (int dt = 0; dt < 4; dt++) acc[mf][dt] = (f32x4){0.f, 0.f, 0.f, 0.f};
        #pragma unroll
        for (int r = 0; r < 4; r++) lsum[mf][r] = 0.f;
    }

    const unsigned short* kbase = kTb + (size_t)(b * NKV + g) * SEQ * 64;
    const unsigned short* vbase = vTb + (size_t)(b * NKV + g) * 64 * SEQ;
    const float EC = 0.125f * 1.44269504f;

    for (int c = 0; c <= qt; ++c) {
        const int k0 = c * 32;
        short8v kf[2][2];
        #pragma unroll
        for (int kt = 0; kt < 2; kt++)
            #pragma unroll
            for (int dc = 0; dc < 2; dc++)
                kf[kt][dc] = *reinterpret_cast<const short8v*>(kbase + (size_t)(k0 + kt * 16 + lr) * 64 + dc * 32 + lg * 8);
        short8v vf[4];
        #pragma unroll
        for (int dt = 0; dt < 4; dt++)
            vf[dt] = *reinterpret_cast<const short8v*>(vbase + (size_t)(dt * 16 + lr) * SEQ + k0 + lg * 8);

        f32x4 S[2][2];
        #pragma unroll
        for (int mf = 0; mf < 2; mf++)
            #pragma unroll
            for (int kt = 0; kt < 2; kt++) {
                f32x4 z = (f32x4){0.f, 0.f, 0.f, 0.f};
                z = __builtin_amdgcn_mfma_f32_16x16x32_bf16(qf[mf][0], kf[kt][0], z, 0, 0, 0);
                S[mf][kt] = __builtin_amdgcn_mfma_f32_16x16x32_bf16(qf[mf][1], kf[kt][1], z, 0, 0, 0);
            }

        const bool diag = (c == qt);
        #pragma unroll
        for (int mf = 0; mf < 2; mf++)
            #pragma unroll
            for (int kt = 0; kt < 2; kt++)
                #pragma unroll
                for (int r = 0; r < 4; r++) {
                    float p = exp2f(S[mf][kt][r] * EC);
                    if (diag) {
                        const int q = q0 + mf * 16 + lg * 4 + r;
                        const int key = k0 + kt * 16 + lr;
                        if (key > q) p = 0.f;
                    }
                    lsum[mf][r] += p;
                    Plds[mf][lg * 4 + r][kt * 16 + lr] = f2bf(p);
                }

        #pragma unroll
        for (int mf = 0; mf < 2; mf++) {
            const short8v pa = *reinterpret_cast<const short8v*>(&Plds[mf][lr][lg * 8]);
            #pragma unroll
            for (int dt = 0; dt < 4; dt++)
                acc[mf][dt] = __builtin_amdgcn_mfma_f32_16x16x32_bf16(pa, vf[dt], acc[mf][dt], 0, 0, 0);
        }
    }

    float invl[2][4];
    #pragma unroll
    for (int mf = 0; mf < 2; mf++)
        #pragma unroll
        for (int r = 0; r < 4; r++) {
            float s = lsum[mf][r];
            s += __shfl_xor(s, 1); s += __shfl_xor(s, 2);
            s += __shfl_xor(s, 4); s += __shfl_xor(s, 8);
            invl[mf][r] = 1.f / s;
        }

    #pragma unroll
    for (int mf = 0; mf < 2; mf++)
        #pragma unroll
        for (int dt = 0; dt < 4; dt++)
            #pragma unroll
            for (int r = 0; r < 4; r++) {
                const int q = q0 + mf * 16 + lg * 4 + r;
                attn_out[(size_t)(b * SEQ + q) * LATENT + h * 64 + dt * 16 + lr] = f2bf(acc[mf][dt][r] * invl[mf][r]);
            }
}

extern "C" void kernel_launch(void* const* d_in, const int* in_sizes, int n_in,
                              void* d_out, int out_size, void* d_ws, size_t ws_size,
                              hipStream_t stream)
{
    const float* x       = (const float*)d_in[0];
    const float* w_qkv   = (const float*)d_in[1];
    const float* w_o     = (const float*)d_in[2];
    const float* qc1_w   = (const float*)d_in[3];
    const float* qc1_b   = (const float*)d_in[4];
    const float* qc2_w   = (const float*)d_in[5];
    const float* qc2_b   = (const float*)d_in[6];
    const float* kc1_w   = (const float*)d_in[7];
    const float* kc1_b   = (const float*)d_in[8];
    const float* kc2_w   = (const float*)d_in[9];
    const float* kc2_b   = (const float*)d_in[10];
    const float* key_temp = (const float*)d_in[11];

    // --- workspace layout (aliased by lifetime) ---
    char* wsb = (char*)d_ws;
    float* qkv = (float*)wsb;                 wsb += (size_t)BS * QKVN * 4;     // 25.2MB; later: qc2+kc2
    float* qc2 = qkv;                                                            // alias (after conv1 done)
    float* kc2 = (float*)((char*)qkv + (size_t)BS * LATENT * 4);                 // alias
    unsigned short* pq  = (unsigned short*)wsb;  wsb += (size_t)NB * SP * LATENT * 2;  // 8.4MB
    unsigned short* pk  = (unsigned short*)wsb;  wsb += (size_t)NB * SP * KVD * 2;     // 2.1MB
    float* qmean = (float*)wsb;  wsb += (size_t)BS * HD * 4;
    float* kmean = (float*)wsb;  wsb += (size_t)BS * HD * 4;
    unsigned short* qTb  = (unsigned short*)wsb;  wsb += (size_t)BS * LATENT * 2;
    unsigned short* kTb  = (unsigned short*)wsb;  wsb += (size_t)BS * KVD * 2;
    unsigned short* vRow = (unsigned short*)wsb;  wsb += (size_t)BS * KVD * 2;
    unsigned short* vTb  = (unsigned short*)wsb;  wsb += (size_t)BS * KVD * 2;
    unsigned short* xb   = (unsigned short*)wsb;  wsb += (size_t)BS * DIMX * 2;  // 33.5MB; later: attnb+wr
    unsigned short* attnb  = xb;                                                 // alias (after qkv GEMM)
    unsigned short* qc2wr  = (unsigned short*)((char*)xb + (size_t)BS * LATENT * 2);
    unsigned short* kc2wr  = (unsigned short*)((char*)qc2wr + (size_t)LATENT * LATENT * 3 * 2);
    unsigned short* wqkvb = (unsigned short*)wsb;  wsb += (size_t)QKVN * DIMX * 2;  // 12.6MB; later: wob
    unsigned short* wob   = wqkvb;                                               // alias (after qkv GEMM)

    float* outp = (float*)d_out;

    // 1. cast A/W for qkv GEMM
    cast_f2b<<<dim3(BS * DIMX / 4 / 256), 256, 0, stream>>>(x, xb, BS * DIMX / 4);
    cast_f2b<<<dim3(QKVN * DIMX / 4 / 256), 256, 0, stream>>>(w_qkv, wqkvb, QKVN * DIMX / 4);
    // 2. qkv projection (bf16 MFMA)
    gemm_bf16<0><<<dim3(QKVN / 128, BS / 128), 256, 0, stream>>>(xb, wqkvb, nullptr, qkv, BS, QKVN, DIMX, 0);
    // 3. prep for later GEMMs (xb/wqkvb now dead; aliases safe in stream order)
    cast_f2b<<<dim3(DIMX * LATENT / 4 / 256), 256, 0, stream>>>(w_o, wob, DIMX * LATENT / 4);
    w3reorder<<<dim3((LATENT * LATENT * 3 + 255) / 256), 256, 0, stream>>>(qc2_w, qc2wr, LATENT, LATENT);
    w3reorder<<<dim3((KVD * KVD * 3 + 255) / 256), 256, 0, stream>>>(kc2_w, kc2wr, KVD, KVD);
    zero_pad<<<dim3(16), 256, 0, stream>>>(pq, pk);
    // 4. means + shifted v, V transpose
    meanv_kernel<<<dim3(BS), 64, 0, stream>>>(qkv, qmean, kmean, vRow);
    vtrans<<<dim3(SEQ / 64, NB * NKV), 256, 0, stream>>>(vRow, vTb);
    // 5. grouped conv1 -> padded bf16
    conv1_grouped<<<dim3(SEQ / 64, NB, NH),  256, 0, stream>>>(qkv, 0,      qc1_w, qc1_b, pq, LATENT);
    conv1_grouped<<<dim3(SEQ / 64, NB, NKV), 256, 0, stream>>>(qkv, LATENT, kc1_w, kc1_b, pk, KVD);
    // 6. conv2 as bf16 GEMM (qc2/kc2 alias qkv -- qkv dead after conv1)
    gemm_bf16<1><<<dim3(LATENT / 128, BS / 128), 256, 0, stream>>>(pq, qc2wr, qc2_b, qc2, BS, LATENT, LATENT * 3, LATENT);
    gemm_bf16<1><<<dim3(KVD / 128,    BS / 128), 256, 0, stream>>>(pk, kc2wr, kc2_b, kc2, BS, KVD,    KVD * 3,    KVD);
    // 7. +0.5*mean, l2norm, rope
    qk_final<<<dim3(BS, NH + NKV), 64, 0, stream>>>(qc2, kc2, qmean, kmean, key_temp, qTb, kTb);
    // 8. attention (bf16 out, aliases xb)
    attn_mfma<<<dim3(SEQ / 32, NB * NH), 64, 0, stream>>>(qTb, kTb, vTb, attnb);
    // 9. output projection
    gemm_bf16<0><<<dim3(DIMX / 128, BS / 128), 256, 0, stream>>>(attnb, wob, nullptr, outp, BS, DIMX, LATENT, 0);
}

// Round 5
// 482.306 us; speedup vs baseline: 8.9793x; 1.0267x over previous
//
#include <hip/hip_runtime.h>
#include <hip/hip_bf16.h>
#include <cstddef>

#define NB 2
#define SEQ 2048
#define DIMX 4096
#define NH 16
#define NKV 4
#define HD 64
#define LATENT 1024
#define KVD 256
#define QKVN 1536
#define BS (NB*SEQ)
#define SP (SEQ+2)   // padded token rows per batch for conv2 input

typedef __attribute__((ext_vector_type(8))) short short8v;   // 8 bf16 = 4 VGPR
typedef __attribute__((ext_vector_type(4))) float f32x4;
typedef __attribute__((ext_vector_type(4))) unsigned short ushort4v;

static __device__ __forceinline__ unsigned short f2bf(float f) {
    union { float f; unsigned u; } v; v.f = f;
    unsigned r = v.u + 0x7fffu + ((v.u >> 16) & 1u);
    return (unsigned short)(r >> 16);
}

static __device__ __forceinline__ void gload_lds16(const unsigned short* g, unsigned short* l) {
    __builtin_amdgcn_global_load_lds((const __attribute__((address_space(1))) void*)g,
                                     (__attribute__((address_space(3))) void*)l, 16, 0, 0);
}

// ---------------- fp32 -> bf16 cast (vectorized x4) ----------------
__global__ __launch_bounds__(256)
void cast_f2b(const float* __restrict__ in, unsigned short* __restrict__ out, int n4)
{
    const int i = blockIdx.x * 256 + threadIdx.x;
    if (i < n4) {
        const float4 v = *reinterpret_cast<const float4*>(in + (size_t)i * 4);
        ushort4v o = {f2bf(v.x), f2bf(v.y), f2bf(v.z), f2bf(v.w)};
        *reinterpret_cast<ushort4v*>(out + (size_t)i * 4) = o;
    }
}

// ---------------- conv2 weight reorder: wr[o][j*I+c] = w[o][c][j], fp32->bf16 ----------------
__global__ __launch_bounds__(256)
void w3reorder(const float* __restrict__ w, unsigned short* __restrict__ wr, int O, int I)
{
    const int idx = blockIdx.x * 256 + threadIdx.x;
    if (idx < O * I * 3) {
        const int o = idx / (I * 3), rem = idx % (I * 3);
        const int j = rem / I, c = rem % I;
        wr[idx] = f2bf(w[(size_t)o * I * 3 + c * 3 + j]);
    }
}

// ---------------- zero the 2 pad rows per batch of the conv2 input buffers ----------------
__global__ __launch_bounds__(256)
void zero_pad(unsigned short* __restrict__ pq, unsigned short* __restrict__ pk)
{
    const int t = blockIdx.x * 256 + threadIdx.x;
    if (t < 2 * 2 * LATENT) {
        const int b = t / (2 * LATENT), r = (t % (2 * LATENT)) / LATENT, c = t % LATENT;
        pq[((size_t)b * SP + r) * LATENT + c] = 0;
    }
    if (t < 2 * 2 * KVD) {
        const int b = t / (2 * KVD), r = (t % (2 * KVD)) / KVD, c = t % KVD;
        pk[((size_t)b * SP + r) * KVD + c] = 0;
    }
}

// ---------------- bf16 MFMA GEMM: C[M][N] = A[M][K] @ W[N][K]^T (+bias), fp32 out ----------------
template<int CONV>
__global__ __launch_bounds__(256)
void gemm_bf16(const unsigned short* __restrict__ A, const unsigned short* __restrict__ W,
               const float* __restrict__ bias, float* __restrict__ C,
               int M, int N, int K, int Cch)
{
    __shared__ unsigned short Abuf[2][128 * 32];
    __shared__ unsigned short Bbuf[2][128 * 32];
    const int n0 = blockIdx.x * 128, m0 = blockIdx.y * 128;
    const int tid = threadIdx.x;
    const int wave = tid >> 6, lane = tid & 63;
    const int lg = lane >> 4, lr = lane & 15;
    const int wm = (wave & 1) * 64, wn = (wave >> 1) * 64;
    const int sr = wave * 32 + (lane >> 2);
    const int sc = (lane & 3) * 8;
    const int bb = m0 / SEQ, s0 = m0 % SEQ;

    const int NT = K / 32;
    f32x4 acc[4][4];
    #pragma unroll
    for (int i = 0; i < 4; i++)
        #pragma unroll
        for (int j = 0; j < 4; j++) acc[i][j] = (f32x4){0.f, 0.f, 0.f, 0.f};

    auto stage = [&](int buf, int kt) {
        const int k0 = kt * 32;
        const unsigned short* ga0;
        if (!CONV) {
            ga0 = A + (size_t)(m0 + sr) * K + k0 + sc;
        } else {
            const int j = k0 / Cch, c0 = k0 - j * Cch;
            ga0 = A + (size_t)(bb * SP + s0 + j + sr) * Cch + c0 + sc;
        }
        const unsigned short* gb0 = W + (size_t)(n0 + sr) * K + k0 + sc;
        const size_t astep = (size_t)16 * (CONV ? Cch : K);
        #pragma unroll
        for (int i = 0; i < 2; i++) {
            gload_lds16(ga0 + i * astep, &Abuf[buf][(wave * 2 + i) * 512]);
            gload_lds16(gb0 + (size_t)i * 16 * K, &Bbuf[buf][(wave * 2 + i) * 512]);
        }
    };

    stage(0, 0);
    __syncthreads();
    int cur = 0;
    for (int kt = 0; kt < NT; ++kt) {
        if (kt + 1 < NT) stage(cur ^ 1, kt + 1);
        short8v af[4], bf[4];
        #pragma unroll
        for (int mi = 0; mi < 4; mi++)
            af[mi] = *reinterpret_cast<const short8v*>(&Abuf[cur][(wm + mi * 16 + lr) * 32 + lg * 8]);
        #pragma unroll
        for (int ni = 0; ni < 4; ni++)
            bf[ni] = *reinterpret_cast<const short8v*>(&Bbuf[cur][(wn + ni * 16 + lr) * 32 + lg * 8]);
        #pragma unroll
        for (int mi = 0; mi < 4; mi++)
            #pragma unroll
            for (int ni = 0; ni < 4; ni++)
                acc[mi][ni] = __builtin_amdgcn_mfma_f32_16x16x32_bf16(af[mi], bf[ni], acc[mi][ni], 0, 0, 0);
        __syncthreads();
        cur ^= 1;
    }

    #pragma unroll
    for (int ni = 0; ni < 4; ni++) {
        const int col = n0 + wn + ni * 16 + lr;
        const float bv = bias ? bias[col] : 0.f;
        #pragma unroll
        for (int mi = 0; mi < 4; mi++)
            #pragma unroll
            for (int r = 0; r < 4; r++)
                C[(size_t)(m0 + wm + mi * 16 + lg * 4 + r) * N + col] = acc[mi][ni][r] + bv;
    }
}

// ---------------- grouped causal conv1 -> bf16 padded [b][SP][CH] (rows 0,1 zero) ----------------
__global__ __launch_bounds__(256)
void conv1_grouped(const float* __restrict__ qkv, int coloff,
                   const float* __restrict__ w, const float* __restrict__ bias,
                   unsigned short* __restrict__ out, int CH)
{
    const int t0 = blockIdx.x * 64;
    const int b  = blockIdx.y;
    const int g  = blockIdx.z;
    __shared__ float xs[66][64];
    for (int idx = threadIdx.x; idx < 66 * 64; idx += 256) {
        const int i = idx >> 6, ic = idx & 63;
        const int tt = t0 + i - 2;
        xs[i][ic] = (tt >= 0) ? qkv[(size_t)(b * SEQ + tt) * QKVN + coloff + g * 64 + ic] : 0.f;
    }
    __syncthreads();
    const int oc = threadIdx.x & 63;
    const int ibase = (threadIdx.x >> 6) * 16;
    float acc[16];
    const float bv = bias[g * 64 + oc];
    #pragma unroll
    for (int i = 0; i < 16; i++) acc[i] = bv;
    const float* wp = w + (size_t)(g * 64 + oc) * 192;
    for (int ic = 0; ic < 64; ic++) {
        const float w0 = wp[ic * 3 + 0], w1 = wp[ic * 3 + 1], w2 = wp[ic * 3 + 2];
        float xv[18];
        #pragma unroll
        for (int r = 0; r < 18; r++) xv[r] = xs[ibase + r][ic];
        #pragma unroll
        for (int i = 0; i < 16; i++) acc[i] += w0 * xv[i] + w1 * xv[i + 1] + w2 * xv[i + 2];
    }
    #pragma unroll
    for (int i = 0; i < 16; i++)
        out[((size_t)b * SP + 2 + t0 + ibase + i) * CH + g * 64 + oc] = f2bf(acc[i]);
}

// ---------------- head means + shifted-v build (row-major bf16) ----------------
__global__ __launch_bounds__(64)
void meanv_kernel(const float* __restrict__ qkv, float* __restrict__ qmean,
                  float* __restrict__ kmean, unsigned short* __restrict__ vRow)
{
    const int t = blockIdx.x, d = threadIdx.x;
    const int b = t >> 11, s = t & (SEQ - 1);
    const float* row = qkv + (size_t)t * QKVN;
    float qs = 0.f;
    #pragma unroll
    for (int h = 0; h < NH; h++) qs += row[h * 64 + d];
    qmean[t * 64 + d] = qs * (1.f / NH);
    float ks = 0.f;
    #pragma unroll
    for (int h = 0; h < NKV; h++) ks += row[LATENT + h * 64 + d];
    kmean[t * 64 + d] = ks * (1.f / NKV);
    #pragma unroll
    for (int g = 0; g < NKV; g++) {
        const int c = g * 64 + d;
        float v;
        if (c < 128) v = row[LATENT + KVD + c];
        else         v = (s > 0) ? qkv[(size_t)(t - 1) * QKVN + LATENT + KVD + 128 + (c - 128)] : 0.f;
        vRow[((size_t)(b * NKV + g) * SEQ + s) * 64 + d] = f2bf(v);
    }
}

// ---------------- V transpose to d-major: vTb[bg][d][S] ----------------
__global__ __launch_bounds__(256)
void vtrans(const unsigned short* __restrict__ vRow, unsigned short* __restrict__ vTb)
{
    const int s0 = blockIdx.x * 64;
    const int bg = blockIdx.y;
    __shared__ unsigned short t[64][72];
    const int tid = threadIdx.x;
    {
        const int r = tid >> 2, c0 = (tid & 3) * 16;
        const unsigned short* p = vRow + ((size_t)bg * SEQ + s0 + r) * 64 + c0;
        const short8v a = *reinterpret_cast<const short8v*>(p);
        const short8v bv = *reinterpret_cast<const short8v*>(p + 8);
        #pragma unroll
        for (int j = 0; j < 8; j++) { t[r][c0 + j] = (unsigned short)a[j]; t[r][c0 + 8 + j] = (unsigned short)bv[j]; }
    }
    __syncthreads();
    {
        const int d = tid >> 2, ss = (tid & 3) * 16;
        short8v o0, o1;
        #pragma unroll
        for (int j = 0; j < 8; j++) { o0[j] = (short)t[ss + j][d]; o1[j] = (short)t[ss + 8 + j][d]; }
        unsigned short* op = vTb + ((size_t)bg * 64 + d) * SEQ + s0 + ss;
        *reinterpret_cast<short8v*>(op) = o0;
        *reinterpret_cast<short8v*>(op + 8) = o1;
    }
}

// ---------------- +0.5*mean, l2norm, rope -> bf16 (B,H,S,D) ----------------
__global__ __launch_bounds__(64)
void qk_final(const float* __restrict__ qc2, const float* __restrict__ kc2,
              const float* __restrict__ qmean, const float* __restrict__ kmean,
              const float* __restrict__ key_temp,
              unsigned short* __restrict__ qTb, unsigned short* __restrict__ kTb)
{
    const int t = blockIdx.x, hh = blockIdx.y, d = threadIdx.x;
    const int b = t >> 11, s = t & (SEQ - 1);
    float val;
    if (hh < NH) val = qc2[(size_t)t * LATENT + hh * 64 + d]        + 0.5f * kmean[t * 64 + d];
    else         val = kc2[(size_t)t * KVD    + (hh - NH) * 64 + d] + 0.5f * qmean[t * 64 + d];
    float ss = val * val;
    #pragma unroll
    for (int off = 32; off >= 1; off >>= 1) ss += __shfl_xor(ss, off);
    const float n = sqrtf(ss);
    val = val / fmaxf(n, 1e-12f);
    if (hh >= NH) val *= key_temp[0];
    const int i = d >> 1;
    const float inv = powf(10000.f, -(float)(2 * i) * (1.f / HD));
    const float ang = (float)s * inv;
    const float cv = cosf(ang), sv = sinf(ang);
    const float partner = __shfl_xor(val, 1);
    const float x1 = (d & 1) ? partner : val;
    const float x2 = (d & 1) ? val : partner;
    const float o = (d & 1) ? (x1 * sv + x2 * cv) : (x1 * cv - x2 * sv);
    if (hh < NH) qTb[((size_t)(b * NH + hh) * SEQ + s) * 64 + d] = f2bf(o);
    else         kTb[((size_t)(b * NKV + (hh - NH)) * SEQ + s) * 64 + d] = f2bf(o);
}

// ---------------- MFMA causal GQA attention, 4 waves split the key range ----------------
// No online max (scores in [-1,1]) => partial numerator/denominator sums over disjoint
// key ranges add. Wave w handles key-tiles c = w, w+4, ... ; LDS reduction at the end.
__global__ __launch_bounds__(256)
void attn_mfma(const unsigned short* __restrict__ qTb, const unsigned short* __restrict__ kTb,
               const unsigned short* __restrict__ vTb, unsigned short* __restrict__ attn_out)
{
    const int qt = 63 - blockIdx.x;          // longest tiles first
    const int bh = blockIdx.y;
    const int b = bh >> 4, h = bh & 15, g = h >> 2;
    const int tid = threadIdx.x;
    const int wave = tid >> 6, lane = tid & 63;
    const int lg = lane >> 4, lr = lane & 15;
    const int q0 = qt * 32;

    // LDS union: [0,32768) = redacc[4][32][64] f32  OR  per-wave Plds (wave*2560, 2x16x40 ushort)
    //            [32768, 33280) = redsum[4][32] f32
    __shared__ __align__(16) char smem[4 * 32 * 64 * 4 + 4 * 32 * 4];
    unsigned short* Plds = (unsigned short*)(smem + wave * 2560);       // [mf][row][key] 40-stride
    float (*redacc)[32][64] = (float (*)[32][64])smem;
    float (*redsum)[32] = (float (*)[32])(smem + 32768);

    short8v qf[2][2];
    const unsigned short* qbase = qTb + ((size_t)(b * NH + h) * SEQ + q0) * 64;
    #pragma unroll
    for (int mf = 0; mf < 2; mf++)
        #pragma unroll
        for (int dc = 0; dc < 2; dc++)
            qf[mf][dc] = *reinterpret_cast<const short8v*>(qbase + (size_t)(mf * 16 + lr) * 64 + dc * 32 + lg * 8);

    f32x4 acc[2][4];
    float lsum[2][4];
    #pragma unroll
    for (int mf = 0; mf < 2; mf++) {
        #pragma unroll
        for (int dt = 0; dt < 4; dt++) acc[mf][dt] = (f32x4){0.f, 0.f, 0.f, 0.f};
        #pragma unroll
        for (int r = 0; r < 4; r++) lsum[mf][r] = 0.f;
    }

    const unsigned short* kbase = kTb + (size_t)(b * NKV + g) * SEQ * 64;
    const unsigned short* vbase = vTb + (size_t)(b * NKV + g) * 64 * SEQ;
    const float EC = 0.125f * 1.44269504f;

    for (int c = wave; c <= qt; c += 4) {
        const int k0 = c * 32;
        short8v kf[2][2];
        #pragma unroll
        for (int kt = 0; kt < 2; kt++)
            #pragma unroll
            for (int dc = 0; dc < 2; dc++)
                kf[kt][dc] = *reinterpret_cast<const short8v*>(kbase + (size_t)(k0 + kt * 16 + lr) * 64 + dc * 32 + lg * 8);
        short8v vf[4];
        #pragma unroll
        for (int dt = 0; dt < 4; dt++)
            vf[dt] = *reinterpret_cast<const short8v*>(vbase + (size_t)(dt * 16 + lr) * SEQ + k0 + lg * 8);

        f32x4 S[2][2];
        #pragma unroll
        for (int mf = 0; mf < 2; mf++)
            #pragma unroll
            for (int kt = 0; kt < 2; kt++) {
                f32x4 z = (f32x4){0.f, 0.f, 0.f, 0.f};
                z = __builtin_amdgcn_mfma_f32_16x16x32_bf16(qf[mf][0], kf[kt][0], z, 0, 0, 0);
                S[mf][kt] = __builtin_amdgcn_mfma_f32_16x16x32_bf16(qf[mf][1], kf[kt][1], z, 0, 0, 0);
            }

        const bool diag = (c == qt);
        #pragma unroll
        for (int mf = 0; mf < 2; mf++)
            #pragma unroll
            for (int kt = 0; kt < 2; kt++)
                #pragma unroll
                for (int r = 0; r < 4; r++) {
                    float p = exp2f(S[mf][kt][r] * EC);
                    if (diag) {
                        const int q = q0 + mf * 16 + lg * 4 + r;
                        const int key = k0 + kt * 16 + lr;
                        if (key > q) p = 0.f;
                    }
                    lsum[mf][r] += p;
                    Plds[mf * 640 + (lg * 4 + r) * 40 + kt * 16 + lr] = f2bf(p);
                }

        #pragma unroll
        for (int mf = 0; mf < 2; mf++) {
            const short8v pa = *reinterpret_cast<const short8v*>(&Plds[mf * 640 + lr * 40 + lg * 8]);
            #pragma unroll
            for (int dt = 0; dt < 4; dt++)
                acc[mf][dt] = __builtin_amdgcn_mfma_f32_16x16x32_bf16(pa, vf[dt], acc[mf][dt], 0, 0, 0);
        }
    }

    __syncthreads();   // all waves done with Plds; safe to overwrite with redacc

    // per-wave partial row-sums (reduce over lr within each 16-lane group)
    #pragma unroll
    for (int mf = 0; mf < 2; mf++)
        #pragma unroll
        for (int r = 0; r < 4; r++) {
            float s = lsum[mf][r];
            s += __shfl_xor(s, 1); s += __shfl_xor(s, 2);
            s += __shfl_xor(s, 4); s += __shfl_xor(s, 8);
            if (lr == 0) redsum[wave][mf * 16 + lg * 4 + r] = s;
        }
    // per-wave partial accumulators, conflict-free layout [w][i][lane]
    #pragma unroll
    for (int mf = 0; mf < 2; mf++)
        #pragma unroll
        for (int dt = 0; dt < 4; dt++)
            #pragma unroll
            for (int r = 0; r < 4; r++)
                redacc[wave][mf * 16 + dt * 4 + r][lane] = acc[mf][dt][r];
    __syncthreads();

    // distributed reduce + normalize + store: thread (wave,lane) does i = wave*8 .. +8
    #pragma unroll
    for (int ii = 0; ii < 8; ii++) {
        const int i = wave * 8 + ii;
        const int mf = i >> 4, dt = (i >> 2) & 3, r = i & 3;
        const int row = mf * 16 + lg * 4 + r;
        const float v = redacc[0][i][lane] + redacc[1][i][lane]
                      + redacc[2][i][lane] + redacc[3][i][lane];
        const float den = redsum[0][row] + redsum[1][row] + redsum[2][row] + redsum[3][row];
        const int q = q0 + row;
        attn_out[(size_t)(b * SEQ + q) * LATENT + h * 64 + dt * 16 + lr] = f2bf(v / den);
    }
}

extern "C" void kernel_launch(void* const* d_in, const int* in_sizes, int n_in,
                              void* d_out, int out_size, void* d_ws, size_t ws_size,
                              hipStream_t stream)
{
    const float* x       = (const float*)d_in[0];
    const float* w_qkv   = (const float*)d_in[1];
    const float* w_o     = (const float*)d_in[2];
    const float* qc1_w   = (const float*)d_in[3];
    const float* qc1_b   = (const float*)d_in[4];
    const float* qc2_w   = (const float*)d_in[5];
    const float* qc2_b   = (const float*)d_in[6];
    const float* kc1_w   = (const float*)d_in[7];
    const float* kc1_b   = (const float*)d_in[8];
    const float* kc2_w   = (const float*)d_in[9];
    const float* kc2_b   = (const float*)d_in[10];
    const float* key_temp = (const float*)d_in[11];

    // --- workspace layout (aliased by lifetime) ---
    char* wsb = (char*)d_ws;
    float* qkv = (float*)wsb;                 wsb += (size_t)BS * QKVN * 4;
    float* qc2 = qkv;
    float* kc2 = (float*)((char*)qkv + (size_t)BS * LATENT * 4);
    unsigned short* pq  = (unsigned short*)wsb;  wsb += (size_t)NB * SP * LATENT * 2;
    unsigned short* pk  = (unsigned short*)wsb;  wsb += (size_t)NB * SP * KVD * 2;
    float* qmean = (float*)wsb;  wsb += (size_t)BS * HD * 4;
    float* kmean = (float*)wsb;  wsb += (size_t)BS * HD * 4;
    unsigned short* qTb  = (unsigned short*)wsb;  wsb += (size_t)BS * LATENT * 2;
    unsigned short* kTb  = (unsigned short*)wsb;  wsb += (size_t)BS * KVD * 2;
    unsigned short* vRow = (unsigned short*)wsb;  wsb += (size_t)BS * KVD * 2;
    unsigned short* vTb  = (unsigned short*)wsb;  wsb += (size_t)BS * KVD * 2;
    unsigned short* xb   = (unsigned short*)wsb;  wsb += (size_t)BS * DIMX * 2;
    unsigned short* attnb  = xb;
    unsigned short* qc2wr  = (unsigned short*)((char*)xb + (size_t)BS * LATENT * 2);
    unsigned short* kc2wr  = (unsigned short*)((char*)qc2wr + (size_t)LATENT * LATENT * 3 * 2);
    unsigned short* wqkvb = (unsigned short*)wsb;  wsb += (size_t)QKVN * DIMX * 2;
    unsigned short* wob   = wqkvb;

    float* outp = (float*)d_out;

    cast_f2b<<<dim3(BS * DIMX / 4 / 256), 256, 0, stream>>>(x, xb, BS * DIMX / 4);
    cast_f2b<<<dim3(QKVN * DIMX / 4 / 256), 256, 0, stream>>>(w_qkv, wqkvb, QKVN * DIMX / 4);
    gemm_bf16<0><<<dim3(QKVN / 128, BS / 128), 256, 0, stream>>>(xb, wqkvb, nullptr, qkv, BS, QKVN, DIMX, 0);
    cast_f2b<<<dim3(DIMX * LATENT / 4 / 256), 256, 0, stream>>>(w_o, wob, DIMX * LATENT / 4);
    w3reorder<<<dim3((LATENT * LATENT * 3 + 255) / 256), 256, 0, stream>>>(qc2_w, qc2wr, LATENT, LATENT);
    w3reorder<<<dim3((KVD * KVD * 3 + 255) / 256), 256, 0, stream>>>(kc2_w, kc2wr, KVD, KVD);
    zero_pad<<<dim3(16), 256, 0, stream>>>(pq, pk);
    meanv_kernel<<<dim3(BS), 64, 0, stream>>>(qkv, qmean, kmean, vRow);
    vtrans<<<dim3(SEQ / 64, NB * NKV), 256, 0, stream>>>(vRow, vTb);
    conv1_grouped<<<dim3(SEQ / 64, NB, NH),  256, 0, stream>>>(qkv, 0,      qc1_w, qc1_b, pq, LATENT);
    conv1_grouped<<<dim3(SEQ / 64, NB, NKV), 256, 0, stream>>>(qkv, LATENT, kc1_w, kc1_b, pk, KVD);
    gemm_bf16<1><<<dim3(LATENT / 128, BS / 128), 256, 0, stream>>>(pq, qc2wr, qc2_b, qc2, BS, LATENT, LATENT * 3, LATENT);
    gemm_bf16<1><<<dim3(KVD / 128,    BS / 128), 256, 0, stream>>>(pk, kc2wr, kc2_b, kc2, BS, KVD,    KVD * 3,    KVD);
    qk_final<<<dim3(BS, NH + NKV), 64, 0, stream>>>(qc2, kc2, qmean, kmean, key_temp, qTb, kTb);
    attn_mfma<<<dim3(SEQ / 32, NB * NH), 256, 0, stream>>>(qTb, kTb, vTb, attnb);
    gemm_bf16<0><<<dim3(DIMX / 128, BS / 128), 256, 0, stream>>>(attnb, wob, nullptr, outp, BS, DIMX, LATENT, 0);
}